// Round 8
// baseline (192.370 us; speedup 1.0000x reference)
//
#include <hip/hip_runtime.h>
#include <hip/hip_bf16.h>
#include <stdint.h>

#define T_TOK 2048
#define H_DIM 1024
#define E_NUM 8
#define I_DIM 512
#define KDOWN (E_NUM * I_DIM) /* 4096 */
#define EPSR 1e-8f

typedef short s16x8 __attribute__((ext_vector_type(8)));
typedef float f32x4 __attribute__((ext_vector_type(4)));

static __device__ __forceinline__ uint16_t f2bf(float f) {
    union { float f; uint32_t i; } v; v.f = f;
    uint32_t lsb = (v.i >> 16) & 1u;
    v.i += 0x7fffu + lsb;                    // round-to-nearest-even
    return (uint16_t)(v.i >> 16);
}

// async global->LDS DMA, 16B/lane; LDS dest = wave-uniform base + lane*16
static __device__ __forceinline__ void gll16(const void* g, void* l) {
    __builtin_amdgcn_global_load_lds(
        (const __attribute__((address_space(1))) void*)g,
        (__attribute__((address_space(3))) void*)l, 16, 0, 0);
}

// ------------- prep: merged weight transpose-cast + routing -------------
// bid<3072: transpose (decoded as old grid (8,16,24)); bid>=3072: routing (512 vblocks)
__global__ __launch_bounds__(256) void prep_kernel(
    const float* __restrict__ wg, const float* __restrict__ wu,
    const float* __restrict__ wd, uint16_t* __restrict__ wgT,
    uint16_t* __restrict__ wuT, uint16_t* __restrict__ wdT,
    const float* __restrict__ x, const float* __restrict__ emb,
    const float* __restrict__ thr, float* __restrict__ scores_out,
    float* __restrict__ gates, uint16_t* __restrict__ xb) {
    __shared__ union {
        float tile[64][68];
        struct { float semb[E_NUM * H_DIM]; float senorm[E_NUM]; } r;
    } sm;
    const int bid = blockIdx.x;
    const int tid = threadIdx.x;

    if (bid < 3072) {   // ---- transpose+cast part ----
        const int bz = bid >> 7, by = (bid >> 3) & 15, bx = bid & 7;
        const float* src; uint16_t* dst; int C, out_stride, r0, c0;
        if (bz < 16) {
            const int e = bz & 7;
            src = (bz < 8 ? wg : wu) + (long)e * H_DIM * I_DIM;
            dst = (bz < 8 ? wgT : wuT) + (long)e * I_DIM * H_DIM;
            C = I_DIM; out_stride = H_DIM;
            r0 = by * 64; c0 = bx * 64;
        } else {
            const int e = bz - 16;
            src = wd + (long)e * I_DIM * H_DIM;
            dst = wdT + (long)e * I_DIM;              // wdT[h][e*512 + i]
            C = H_DIM; out_stride = KDOWN;
            r0 = bx * 64; c0 = by * 64;
        }
        const int g16 = tid >> 4, l16 = (tid & 15) * 4;
        #pragma unroll
        for (int it = 0; it < 4; ++it) {
            int r = it * 16 + g16;
            *(float4*)&sm.tile[r][l16] = *(const float4*)(src + (long)(r0 + r) * C + c0 + l16);
        }
        __syncthreads();
        #pragma unroll
        for (int it = 0; it < 4; ++it) {
            int oc = it * 16 + g16;
            ushort4 o;
            o.x = f2bf(sm.tile[l16 + 0][oc]);
            o.y = f2bf(sm.tile[l16 + 1][oc]);
            o.z = f2bf(sm.tile[l16 + 2][oc]);
            o.w = f2bf(sm.tile[l16 + 3][oc]);
            *(ushort4*)(dst + (long)(c0 + oc) * out_stride + r0 + l16) = o;
        }
        return;
    }
    // ---- routing part: cosine scores + masked softmax gates + bf16 cast of x ----
    const int rb = bid - 3072;
    const int lane = tid & 63;
    const int wave = tid >> 6;
    for (int i = tid; i < E_NUM * H_DIM; i += 256) sm.r.semb[i] = emb[i];
    __syncthreads();
    for (int e = wave; e < E_NUM; e += 4) {
        float s = 0.f;
        #pragma unroll
        for (int c = 0; c < 16; ++c) { float v = sm.r.semb[e * H_DIM + lane + 64 * c]; s += v * v; }
        #pragma unroll
        for (int off = 32; off; off >>= 1) s += __shfl_xor(s, off);
        if (lane == 0) sm.r.senorm[e] = fmaxf(sqrtf(s), EPSR);
    }
    __syncthreads();
    const int t = rb * 4 + wave;
    const float* xt = x + (long)t * H_DIM;
    uint16_t* xbt = xb + (long)t * H_DIM;
    float nrm = 0.f, dot[E_NUM];
    #pragma unroll
    for (int e = 0; e < E_NUM; ++e) dot[e] = 0.f;
    #pragma unroll
    for (int c = 0; c < 16; ++c) {
        float v = xt[lane + 64 * c];
        xbt[lane + 64 * c] = f2bf(v);
        nrm += v * v;
        #pragma unroll
        for (int e = 0; e < E_NUM; ++e) dot[e] += v * sm.r.semb[e * H_DIM + lane + 64 * c];
    }
    #pragma unroll
    for (int off = 32; off; off >>= 1) {
        nrm += __shfl_xor(nrm, off);
        #pragma unroll
        for (int e = 0; e < E_NUM; ++e) dot[e] += __shfl_xor(dot[e], off);
    }
    float xn = fmaxf(sqrtf(nrm), EPSR);
    float sc[E_NUM], sel[E_NUM];
    float msel = -1e30f, mall = -1e30f;
    int nsel = 0, arg = 0;
    #pragma unroll
    for (int e = 0; e < E_NUM; ++e) {
        sc[e] = dot[e] / (xn * sm.r.senorm[e]);
        float d = sc[e] - thr[e];
        sel[e] = (d > 0.f) ? 1.f : 0.f;                 // silu(d) > 0  <=>  d > 0
        if (d > 0.f) { nsel++; msel = fmaxf(msel, sc[e]); }
        if (sc[e] > mall) { mall = sc[e]; arg = e; }
    }
    float w[E_NUM], den = 0.f;
    #pragma unroll
    for (int e = 0; e < E_NUM; ++e) { w[e] = (sel[e] > 0.f) ? __expf(sc[e] - msel) : 0.f; den += w[e]; }
    if (lane == 0) {
        #pragma unroll
        for (int e = 0; e < E_NUM; ++e) {
            scores_out[t * E_NUM + e] = sc[e];
            gates[t * E_NUM + e] = (nsel > 0) ? (w[e] / den) : ((e == arg) ? 1.f : 0.f);
        }
    }
}

// ---------------- gate/up GEMM + silu*up*gate -> Hmid bf16 ----------------
// grid (T/128, I/128, E) = (16,4,8)=512 blocks; 4 waves 2x2, wave-tile 64x64 DUAL.
// (256,2): the 128-VGPR dual accumulator structurally needs ~190 VGPRs;
// forcing 3 waves/SIMD (r6) spilled to scratch (+650MB traffic, 5x slower).
// At ~905 TF effective this sits on the documented m97-structure plateau.
__global__ __launch_bounds__(256, 2) void moe_gateup_kernel(
    const uint16_t* __restrict__ xb,    // [2048][1024]
    const uint16_t* __restrict__ wgT,   // [8][512][1024]
    const uint16_t* __restrict__ wuT,   // [8][512][1024]
    const float* __restrict__ gates,    // [2048][8]
    uint16_t* __restrict__ hmid) {      // [2048][4096] = [t][e*512+i]
    const int e  = blockIdx.z;
    const int t0 = blockIdx.x * 128;
    const int i0 = blockIdx.y * 128;
    __shared__ uint16_t sA[128][64];
    __shared__ uint16_t sG[128][64];
    __shared__ uint16_t sU[128][64];
    __shared__ float sGate[128];
    const int tid  = threadIdx.x;
    const int lane = tid & 63;
    const int wave = tid >> 6;
    const int wm = wave >> 1, wn = wave & 1;
    if (tid < 128) sGate[tid] = gates[(t0 + tid) * E_NUM + e];

    const int srow = wave * 32 + (lane >> 3);
    const int scol = ((lane & 7) ^ (srow & 7)) * 8;   // XOR-swizzled chunk
    const uint16_t* ga = xb  + (long)(t0 + srow) * H_DIM + scol;
    const uint16_t* gg = wgT + ((long)e * I_DIM + i0 + srow) * H_DIM + scol;
    const uint16_t* gu = wuT + ((long)e * I_DIM + i0 + srow) * H_DIM + scol;

    f32x4 accg[4][4] = {}, accu[4][4] = {};
    const int q = lane >> 4, r16 = lane & 15;
    const int sw = r16 & 7;

    for (int kb = 0; kb < H_DIM; kb += 64) {
        __syncthreads();
        #pragma unroll
        for (int j = 0; j < 4; ++j) {
            const int lr = wave * 32 + j * 8;
            gll16(ga + (long)j * 8 * H_DIM + kb, &sA[lr][0]);
            gll16(gg + (long)j * 8 * H_DIM + kb, &sG[lr][0]);
            gll16(gu + (long)j * 8 * H_DIM + kb, &sU[lr][0]);
        }
        __syncthreads();
        #pragma unroll
        for (int kk = 0; kk < 2; ++kk) {
            const int pc = ((kk * 4 + q) ^ sw) * 8;
            s16x8 af[4], gf[4], uf[4];
            #pragma unroll
            for (int m = 0; m < 4; ++m)
                af[m] = *(const s16x8*)&sA[wm * 64 + m * 16 + r16][pc];
            #pragma unroll
            for (int n = 0; n < 4; ++n) {
                gf[n] = *(const s16x8*)&sG[wn * 64 + n * 16 + r16][pc];
                uf[n] = *(const s16x8*)&sU[wn * 64 + n * 16 + r16][pc];
            }
            #pragma unroll
            for (int m = 0; m < 4; ++m)
                #pragma unroll
                for (int n = 0; n < 4; ++n) {
                    accg[m][n] = __builtin_amdgcn_mfma_f32_16x16x32_bf16(af[m], gf[n], accg[m][n], 0, 0, 0);
                    accu[m][n] = __builtin_amdgcn_mfma_f32_16x16x32_bf16(af[m], uf[n], accu[m][n], 0, 0, 0);
                }
        }
    }
    #pragma unroll
    for (int m = 0; m < 4; ++m) {
        #pragma unroll
        for (int rr = 0; rr < 4; ++rr) {
            const int trow = wm * 64 + m * 16 + q * 4 + rr;
            const float gate = sGate[trow];
            const long base = (long)(t0 + trow) * KDOWN + e * I_DIM + i0;
            #pragma unroll
            for (int n = 0; n < 4; ++n) {
                float g = accg[m][n][rr], u = accu[m][n][rr];
                float h = gate * (g / (1.f + __expf(-g))) * u;
                hmid[base + wn * 64 + n * 16 + r16] = f2bf(h);
            }
        }
    }
}

// ---------------- down GEMM: split-K=4, all slices atomicAdd into zeroed out ----------------
// grid (H/128, T/128, 4): x=h fastest so consecutive blocks share the hmid tile.
// No partials / no reduce kernel: each output element receives exactly 4 fp32
// atomic adds (light contention); out is memset-0 before this launch.
__global__ __launch_bounds__(256, 3) void moe_down_kernel(
    const uint16_t* __restrict__ hmid,  // [2048][4096]
    const uint16_t* __restrict__ wdT,   // [1024][4096]
    float* __restrict__ out) {          // [2048][1024], pre-zeroed
    const int h0 = blockIdx.x * 128;
    const int t0 = blockIdx.y * 128;
    const int kz = blockIdx.z;
    const int kst = kz * 1024;
    __shared__ uint16_t sA[128][64];
    __shared__ uint16_t sB[128][64];
    const int tid  = threadIdx.x;
    const int lane = tid & 63;
    const int wave = tid >> 6;
    const int wm = wave >> 1, wn = wave & 1;

    const int srow = wave * 32 + (lane >> 3);
    const int scol = ((lane & 7) ^ (srow & 7)) * 8;
    const uint16_t* ga = hmid + (long)(t0 + srow) * KDOWN + scol;
    const uint16_t* gb = wdT  + (long)(h0 + srow) * KDOWN + scol;

    f32x4 acc[4][4] = {};
    const int q = lane >> 4, r16 = lane & 15;
    const int sw = r16 & 7;

    for (int kb = kst; kb < kst + 1024; kb += 64) {
        __syncthreads();
        #pragma unroll
        for (int j = 0; j < 4; ++j) {
            const int lr = wave * 32 + j * 8;
            gll16(ga + (long)j * 8 * KDOWN + kb, &sA[lr][0]);
            gll16(gb + (long)j * 8 * KDOWN + kb, &sB[lr][0]);
        }
        __syncthreads();
        #pragma unroll
        for (int kk = 0; kk < 2; ++kk) {
            const int pc = ((kk * 4 + q) ^ sw) * 8;
            s16x8 af[4], bf[4];
            #pragma unroll
            for (int m = 0; m < 4; ++m)
                af[m] = *(const s16x8*)&sA[wm * 64 + m * 16 + r16][pc];
            #pragma unroll
            for (int n = 0; n < 4; ++n)
                bf[n] = *(const s16x8*)&sB[wn * 64 + n * 16 + r16][pc];
            #pragma unroll
            for (int m = 0; m < 4; ++m)
                #pragma unroll
                for (int n = 0; n < 4; ++n)
                    acc[m][n] = __builtin_amdgcn_mfma_f32_16x16x32_bf16(af[m], bf[n], acc[m][n], 0, 0, 0);
        }
    }
    #pragma unroll
    for (int m = 0; m < 4; ++m) {
        #pragma unroll
        for (int rr = 0; rr < 4; ++rr) {
            const int t = t0 + wm * 64 + m * 16 + q * 4 + rr;
            #pragma unroll
            for (int n = 0; n < 4; ++n)
                atomicAdd(&out[(long)t * H_DIM + h0 + wn * 64 + n * 16 + r16], acc[m][n][rr]);
        }
    }
}

extern "C" void kernel_launch(void* const* d_in, const int* in_sizes, int n_in,
                              void* d_out, int out_size, void* d_ws, size_t ws_size,
                              hipStream_t stream) {
    const float* x    = (const float*)d_in[0];   // [2,1024,1024]
    const float* emb  = (const float*)d_in[1];   // [8,1024]
    const float* thr  = (const float*)d_in[2];   // [8]
    const float* wg   = (const float*)d_in[3];   // [8,1024,512]
    const float* wu   = (const float*)d_in[4];   // [8,1024,512]
    const float* wd   = (const float*)d_in[5];   // [8,512,1024]
    float* out    = (float*)d_out;               // [2048][1024]
    float* scores = out + (size_t)T_TOK * H_DIM; // [2048][8]

    uint8_t* ws = (uint8_t*)d_ws;
    uint16_t* xb   = (uint16_t*)(ws);                         //  4 MB  x bf16
    uint16_t* wgT  = (uint16_t*)(ws + (size_t)4  * 1048576);  //  8 MB  [E][I][H]
    uint16_t* wuT  = (uint16_t*)(ws + (size_t)12 * 1048576);  //  8 MB  [E][I][H]
    uint16_t* wdT  = (uint16_t*)(ws + (size_t)20 * 1048576);  //  8 MB  [H][E*I]
    uint16_t* hmid = (uint16_t*)(ws + (size_t)28 * 1048576);  // 16 MB  [T][E*I]
    float*    gates = (float*)  (ws + (size_t)44 * 1048576);  // 64 KB  [T][E]

    // zero the accumulation target (scores tail is written by prep, not memset)
    hipMemsetAsync(out, 0, (size_t)T_TOK * H_DIM * sizeof(float), stream);

    prep_kernel<<<3072 + T_TOK / 4, 256, 0, stream>>>(
        wg, wu, wd, wgT, wuT, wdT, x, emb, thr, scores, gates, xb);
    moe_gateup_kernel<<<dim3(T_TOK / 128, I_DIM / 128, E_NUM), 256, 0, stream>>>(
        xb, wgT, wuT, gates, hmid);
    moe_down_kernel<<<dim3(H_DIM / 128, T_TOK / 128, 4), 256, 0, stream>>>(hmid, wdT, out);
}

// Round 9
// 177.534 us; speedup vs baseline: 1.0836x; 1.0836x over previous
//
#include <hip/hip_runtime.h>
#include <hip/hip_bf16.h>
#include <stdint.h>

#define T_TOK 2048
#define H_DIM 1024
#define E_NUM 8
#define I_DIM 512
#define KDOWN (E_NUM * I_DIM) /* 4096 */
#define EPSR 1e-8f

typedef short s16x8 __attribute__((ext_vector_type(8)));
typedef float f32x4 __attribute__((ext_vector_type(4)));

static __device__ __forceinline__ uint16_t f2bf(float f) {
    union { float f; uint32_t i; } v; v.f = f;
    uint32_t lsb = (v.i >> 16) & 1u;
    v.i += 0x7fffu + lsb;                    // round-to-nearest-even
    return (uint16_t)(v.i >> 16);
}

// async global->LDS DMA, 16B/lane; LDS dest = wave-uniform base + lane*16
static __device__ __forceinline__ void gll16(const void* g, void* l) {
    __builtin_amdgcn_global_load_lds(
        (const __attribute__((address_space(1))) void*)g,
        (__attribute__((address_space(3))) void*)l, 16, 0, 0);
}

// ------------- prep: merged weight transpose-cast + routing -------------
// bid<3072: transpose (decoded as old grid (8,16,24)); bid>=3072: routing (512 vblocks)
__global__ __launch_bounds__(256) void prep_kernel(
    const float* __restrict__ wg, const float* __restrict__ wu,
    const float* __restrict__ wd, uint16_t* __restrict__ wgT,
    uint16_t* __restrict__ wuT, uint16_t* __restrict__ wdT,
    const float* __restrict__ x, const float* __restrict__ emb,
    const float* __restrict__ thr, float* __restrict__ scores_out,
    float* __restrict__ gates, uint16_t* __restrict__ xb) {
    __shared__ union {
        float tile[64][68];
        struct { float semb[E_NUM * H_DIM]; float senorm[E_NUM]; } r;
    } sm;
    const int bid = blockIdx.x;
    const int tid = threadIdx.x;

    if (bid < 3072) {   // ---- transpose+cast part ----
        const int bz = bid >> 7, by = (bid >> 3) & 15, bx = bid & 7;
        const float* src; uint16_t* dst; int C, out_stride, r0, c0;
        if (bz < 16) {
            const int e = bz & 7;
            src = (bz < 8 ? wg : wu) + (long)e * H_DIM * I_DIM;
            dst = (bz < 8 ? wgT : wuT) + (long)e * I_DIM * H_DIM;
            C = I_DIM; out_stride = H_DIM;
            r0 = by * 64; c0 = bx * 64;
        } else {
            const int e = bz - 16;
            src = wd + (long)e * I_DIM * H_DIM;
            dst = wdT + (long)e * I_DIM;              // wdT[h][e*512 + i]
            C = H_DIM; out_stride = KDOWN;
            r0 = bx * 64; c0 = by * 64;
        }
        const int g16 = tid >> 4, l16 = (tid & 15) * 4;
        #pragma unroll
        for (int it = 0; it < 4; ++it) {
            int r = it * 16 + g16;
            *(float4*)&sm.tile[r][l16] = *(const float4*)(src + (long)(r0 + r) * C + c0 + l16);
        }
        __syncthreads();
        #pragma unroll
        for (int it = 0; it < 4; ++it) {
            int oc = it * 16 + g16;
            ushort4 o;
            o.x = f2bf(sm.tile[l16 + 0][oc]);
            o.y = f2bf(sm.tile[l16 + 1][oc]);
            o.z = f2bf(sm.tile[l16 + 2][oc]);
            o.w = f2bf(sm.tile[l16 + 3][oc]);
            *(ushort4*)(dst + (long)(c0 + oc) * out_stride + r0 + l16) = o;
        }
        return;
    }
    // ---- routing part: cosine scores + masked softmax gates + bf16 cast of x ----
    const int rb = bid - 3072;
    const int lane = tid & 63;
    const int wave = tid >> 6;
    for (int i = tid; i < E_NUM * H_DIM; i += 256) sm.r.semb[i] = emb[i];
    __syncthreads();
    for (int e = wave; e < E_NUM; e += 4) {
        float s = 0.f;
        #pragma unroll
        for (int c = 0; c < 16; ++c) { float v = sm.r.semb[e * H_DIM + lane + 64 * c]; s += v * v; }
        #pragma unroll
        for (int off = 32; off; off >>= 1) s += __shfl_xor(s, off);
        if (lane == 0) sm.r.senorm[e] = fmaxf(sqrtf(s), EPSR);
    }
    __syncthreads();
    const int t = rb * 4 + wave;
    const float* xt = x + (long)t * H_DIM;
    uint16_t* xbt = xb + (long)t * H_DIM;
    float nrm = 0.f, dot[E_NUM];
    #pragma unroll
    for (int e = 0; e < E_NUM; ++e) dot[e] = 0.f;
    #pragma unroll
    for (int c = 0; c < 16; ++c) {
        float v = xt[lane + 64 * c];
        xbt[lane + 64 * c] = f2bf(v);
        nrm += v * v;
        #pragma unroll
        for (int e = 0; e < E_NUM; ++e) dot[e] += v * sm.r.semb[e * H_DIM + lane + 64 * c];
    }
    #pragma unroll
    for (int off = 32; off; off >>= 1) {
        nrm += __shfl_xor(nrm, off);
        #pragma unroll
        for (int e = 0; e < E_NUM; ++e) dot[e] += __shfl_xor(dot[e], off);
    }
    float xn = fmaxf(sqrtf(nrm), EPSR);
    float sc[E_NUM], sel[E_NUM];
    float msel = -1e30f, mall = -1e30f;
    int nsel = 0, arg = 0;
    #pragma unroll
    for (int e = 0; e < E_NUM; ++e) {
        sc[e] = dot[e] / (xn * sm.r.senorm[e]);
        float d = sc[e] - thr[e];
        sel[e] = (d > 0.f) ? 1.f : 0.f;                 // silu(d) > 0  <=>  d > 0
        if (d > 0.f) { nsel++; msel = fmaxf(msel, sc[e]); }
        if (sc[e] > mall) { mall = sc[e]; arg = e; }
    }
    float w[E_NUM], den = 0.f;
    #pragma unroll
    for (int e = 0; e < E_NUM; ++e) { w[e] = (sel[e] > 0.f) ? __expf(sc[e] - msel) : 0.f; den += w[e]; }
    if (lane == 0) {
        #pragma unroll
        for (int e = 0; e < E_NUM; ++e) {
            scores_out[t * E_NUM + e] = sc[e];
            gates[t * E_NUM + e] = (nsel > 0) ? (w[e] / den) : ((e == arg) ? 1.f : 0.f);
        }
    }
}

// ---------------- gate/up GEMM + silu*up*gate -> Hmid bf16 ----------------
// grid (T/128, I/128, E) = (16,4,8)=512 blocks; 4 waves 2x2, wave-tile 64x64 DUAL.
// (256,2): the 128-VGPR dual accumulator structurally needs ~190 VGPRs;
// forcing 3 waves/SIMD (r6) spilled to scratch (+650MB traffic, 5x slower).
__global__ __launch_bounds__(256, 2) void moe_gateup_kernel(
    const uint16_t* __restrict__ xb,    // [2048][1024]
    const uint16_t* __restrict__ wgT,   // [8][512][1024]
    const uint16_t* __restrict__ wuT,   // [8][512][1024]
    const float* __restrict__ gates,    // [2048][8]
    uint16_t* __restrict__ hmid) {      // [2048][4096] = [t][e*512+i]
    const int e  = blockIdx.z;
    const int t0 = blockIdx.x * 128;
    const int i0 = blockIdx.y * 128;
    __shared__ uint16_t sA[128][64];
    __shared__ uint16_t sG[128][64];
    __shared__ uint16_t sU[128][64];
    __shared__ float sGate[128];
    const int tid  = threadIdx.x;
    const int lane = tid & 63;
    const int wave = tid >> 6;
    const int wm = wave >> 1, wn = wave & 1;
    if (tid < 128) sGate[tid] = gates[(t0 + tid) * E_NUM + e];

    const int srow = wave * 32 + (lane >> 3);
    const int scol = ((lane & 7) ^ (srow & 7)) * 8;   // XOR-swizzled chunk
    const uint16_t* ga = xb  + (long)(t0 + srow) * H_DIM + scol;
    const uint16_t* gg = wgT + ((long)e * I_DIM + i0 + srow) * H_DIM + scol;
    const uint16_t* gu = wuT + ((long)e * I_DIM + i0 + srow) * H_DIM + scol;

    f32x4 accg[4][4] = {}, accu[4][4] = {};
    const int q = lane >> 4, r16 = lane & 15;
    const int sw = r16 & 7;

    for (int kb = 0; kb < H_DIM; kb += 64) {
        __syncthreads();
        #pragma unroll
        for (int j = 0; j < 4; ++j) {
            const int lr = wave * 32 + j * 8;
            gll16(ga + (long)j * 8 * H_DIM + kb, &sA[lr][0]);
            gll16(gg + (long)j * 8 * H_DIM + kb, &sG[lr][0]);
            gll16(gu + (long)j * 8 * H_DIM + kb, &sU[lr][0]);
        }
        __syncthreads();
        #pragma unroll
        for (int kk = 0; kk < 2; ++kk) {
            const int pc = ((kk * 4 + q) ^ sw) * 8;
            s16x8 af[4], gf[4], uf[4];
            #pragma unroll
            for (int m = 0; m < 4; ++m)
                af[m] = *(const s16x8*)&sA[wm * 64 + m * 16 + r16][pc];
            #pragma unroll
            for (int n = 0; n < 4; ++n) {
                gf[n] = *(const s16x8*)&sG[wn * 64 + n * 16 + r16][pc];
                uf[n] = *(const s16x8*)&sU[wn * 64 + n * 16 + r16][pc];
            }
            #pragma unroll
            for (int m = 0; m < 4; ++m)
                #pragma unroll
                for (int n = 0; n < 4; ++n) {
                    accg[m][n] = __builtin_amdgcn_mfma_f32_16x16x32_bf16(af[m], gf[n], accg[m][n], 0, 0, 0);
                    accu[m][n] = __builtin_amdgcn_mfma_f32_16x16x32_bf16(af[m], uf[n], accu[m][n], 0, 0, 0);
                }
        }
    }
    #pragma unroll
    for (int m = 0; m < 4; ++m) {
        #pragma unroll
        for (int rr = 0; rr < 4; ++rr) {
            const int trow = wm * 64 + m * 16 + q * 4 + rr;
            const float gate = sGate[trow];
            const long base = (long)(t0 + trow) * KDOWN + e * I_DIM + i0;
            #pragma unroll
            for (int n = 0; n < 4; ++n) {
                float g = accg[m][n][rr], u = accu[m][n][rr];
                float h = gate * (g / (1.f + __expf(-g))) * u;
                hmid[base + wn * 64 + n * 16 + r16] = f2bf(h);
            }
        }
    }
}

// ---------------- down GEMM: split-K=4; kz0 -> out, kz1..3 -> fp32 partials ----------------
// grid (H/128, T/128, 4): x=h fastest so consecutive blocks share the hmid tile.
// Single 64-VGPR accumulator -> (256,3) fits without spill (verified r5: VGPR~128).
__global__ __launch_bounds__(256, 3) void moe_down_kernel(
    const uint16_t* __restrict__ hmid,  // [2048][4096]
    const uint16_t* __restrict__ wdT,   // [1024][4096]
    float* __restrict__ out,            // [2048][1024]
    float* __restrict__ parts) {        // [3][2048][1024]
    const int h0 = blockIdx.x * 128;
    const int t0 = blockIdx.y * 128;
    const int kz = blockIdx.z;
    const int kst = kz * 1024;
    __shared__ uint16_t sA[128][64];
    __shared__ uint16_t sB[128][64];
    const int tid  = threadIdx.x;
    const int lane = tid & 63;
    const int wave = tid >> 6;
    const int wm = wave >> 1, wn = wave & 1;

    const int srow = wave * 32 + (lane >> 3);
    const int scol = ((lane & 7) ^ (srow & 7)) * 8;
    const uint16_t* ga = hmid + (long)(t0 + srow) * KDOWN + scol;
    const uint16_t* gb = wdT  + (long)(h0 + srow) * KDOWN + scol;

    f32x4 acc[4][4] = {};
    const int q = lane >> 4, r16 = lane & 15;
    const int sw = r16 & 7;

    for (int kb = kst; kb < kst + 1024; kb += 64) {
        __syncthreads();
        #pragma unroll
        for (int j = 0; j < 4; ++j) {
            const int lr = wave * 32 + j * 8;
            gll16(ga + (long)j * 8 * KDOWN + kb, &sA[lr][0]);
            gll16(gb + (long)j * 8 * KDOWN + kb, &sB[lr][0]);
        }
        __syncthreads();
        #pragma unroll
        for (int kk = 0; kk < 2; ++kk) {
            const int pc = ((kk * 4 + q) ^ sw) * 8;
            s16x8 af[4], bf[4];
            #pragma unroll
            for (int m = 0; m < 4; ++m)
                af[m] = *(const s16x8*)&sA[wm * 64 + m * 16 + r16][pc];
            #pragma unroll
            for (int n = 0; n < 4; ++n)
                bf[n] = *(const s16x8*)&sB[wn * 64 + n * 16 + r16][pc];
            #pragma unroll
            for (int m = 0; m < 4; ++m)
                #pragma unroll
                for (int n = 0; n < 4; ++n)
                    acc[m][n] = __builtin_amdgcn_mfma_f32_16x16x32_bf16(af[m], bf[n], acc[m][n], 0, 0, 0);
        }
    }
    float* dst = (kz == 0) ? out : (parts + (long)(kz - 1) * T_TOK * H_DIM);
    #pragma unroll
    for (int m = 0; m < 4; ++m) {
        #pragma unroll
        for (int rr = 0; rr < 4; ++rr) {
            const int t = t0 + wm * 64 + m * 16 + q * 4 + rr;
            #pragma unroll
            for (int n = 0; n < 4; ++n)
                dst[(long)t * H_DIM + h0 + wn * 64 + n * 16 + r16] = acc[m][n][rr];
        }
    }
}

// ---------------- reduce: out += part0..part2 ----------------
__global__ __launch_bounds__(256) void reduce_kernel(float* __restrict__ out,
                                                     const float* __restrict__ parts) {
    long i = ((long)blockIdx.x * 256 + threadIdx.x) * 4;
    float4 a = *(const float4*)(out + i);
    #pragma unroll
    for (int j = 0; j < 3; ++j) {
        float4 b = *(const float4*)(parts + (long)j * T_TOK * H_DIM + i);
        a.x += b.x; a.y += b.y; a.z += b.z; a.w += b.w;
    }
    *(float4*)(out + i) = a;
}

extern "C" void kernel_launch(void* const* d_in, const int* in_sizes, int n_in,
                              void* d_out, int out_size, void* d_ws, size_t ws_size,
                              hipStream_t stream) {
    const float* x    = (const float*)d_in[0];   // [2,1024,1024]
    const float* emb  = (const float*)d_in[1];   // [8,1024]
    const float* thr  = (const float*)d_in[2];   // [8]
    const float* wg   = (const float*)d_in[3];   // [8,1024,512]
    const float* wu   = (const float*)d_in[4];   // [8,1024,512]
    const float* wd   = (const float*)d_in[5];   // [8,512,1024]
    float* out    = (float*)d_out;               // [2048][1024]
    float* scores = out + (size_t)T_TOK * H_DIM; // [2048][8]

    uint8_t* ws = (uint8_t*)d_ws;
    uint16_t* xb   = (uint16_t*)(ws);                         //  4 MB  x bf16
    uint16_t* wgT  = (uint16_t*)(ws + (size_t)4  * 1048576);  //  8 MB  [E][I][H]
    uint16_t* wuT  = (uint16_t*)(ws + (size_t)12 * 1048576);  //  8 MB  [E][I][H]
    uint16_t* wdT  = (uint16_t*)(ws + (size_t)20 * 1048576);  //  8 MB  [H][E*I]
    uint16_t* hmid = (uint16_t*)(ws + (size_t)28 * 1048576);  // 16 MB  [T][E*I]
    float*    gates = (float*)  (ws + (size_t)44 * 1048576);  // 64 KB  [T][E]
    float*    parts = (float*)  (ws + (size_t)48 * 1048576);  // 24 MB  [3][T][H]

    prep_kernel<<<3072 + T_TOK / 4, 256, 0, stream>>>(
        wg, wu, wd, wgT, wuT, wdT, x, emb, thr, scores, gates, xb);
    moe_gateup_kernel<<<dim3(T_TOK / 128, I_DIM / 128, E_NUM), 256, 0, stream>>>(
        xb, wgT, wuT, gates, hmid);
    moe_down_kernel<<<dim3(H_DIM / 128, T_TOK / 128, 4), 256, 0, stream>>>(hmid, wdT, out, parts);
    reduce_kernel<<<(T_TOK * H_DIM) / 1024, 256, 0, stream>>>(out, parts);
}